// Round 11
// baseline (175.511 us; speedup 1.0000x reference)
//
#include <hip/hip_runtime.h>
#include <cstddef>
#include <cstdint>

// CausalSelfAttention, bf16-MFMA pipeline, round 11.
// B=4, T=2048, C=1024, NH=16, HS=64.
//   prep:      x fp32 -> bf16  +  W fp32 [K][N] -> W^T bf16 [N][K] (fused)
//   gemm_qkv:  fused q/k/v projection; BK=64, XOR-swizzled LDS, bm-sliced XCD
//   gemm_bt<2>: output projection
//   attn_big:  flash attention; UNPAIRED 128-q-tile blocks, KVB=64 dbuf
//              (32 KB LDS), VGPR target <=64 -> 4 blocks/CU / 32 waves;
//              per-CU work balanced via qt/bh grid mapping (co-resident
//              blocks get {p, 15-p, p, 15-p}); swapped QK^T, in-lane softmax,
//              b128 PV via pi-permuted V, hoisted LDS offsets.

namespace {

typedef unsigned short u16;
typedef unsigned int u32;
typedef __attribute__((ext_vector_type(8))) short s8v;   // 8 bf16 (4 VGPR)
typedef __attribute__((ext_vector_type(4))) short s4v;   // 4 bf16 (2 VGPR)
typedef __attribute__((ext_vector_type(4))) float f4v;

constexpr int Bn = 4, Tn = 2048, Cn = 1024;
constexpr int Mn = Bn * Tn;  // 8192
constexpr float QSCALE = 0.125f * 1.44269504f;  // 1/sqrt(64) * log2(e)

__device__ __forceinline__ u16 bfc(float f) {  // fp32 -> bf16 (RNE, native)
  return __builtin_bit_cast(u16, (__bf16)f);
}

__device__ __forceinline__ float ex2(float x) {
#if __has_builtin(__builtin_amdgcn_exp2f)
  return __builtin_amdgcn_exp2f(x);
#else
  return exp2f(x);
#endif
}

__device__ __forceinline__ f4v mfma16(s8v a, s8v b, f4v c) {
  return __builtin_amdgcn_mfma_f32_16x16x32_bf16(a, b, c, 0, 0, 0);
}

__device__ __forceinline__ f4v mfma16k16(s4v a, s4v b, f4v c) {
#if __has_builtin(__builtin_amdgcn_mfma_f32_16x16x16bf16_1k)
  return __builtin_amdgcn_mfma_f32_16x16x16bf16_1k(a, b, c, 0, 0, 0);
#else
  f4v d = c;
  asm("v_mfma_f32_16x16x16_bf16 %0, %1, %2, %0" : "+v"(d) : "v"(a), "v"(b));
  return d;
#endif
}

typedef __attribute__((address_space(1))) const u32 gas_u32;
typedef __attribute__((address_space(3))) u32 las_u32;
__device__ __forceinline__ void gl_lds16(const void* g, void* l) {
  __builtin_amdgcn_global_load_lds((gas_u32*)g, (las_u32*)l, 16, 0, 0);
}

// ---------------- prep: cvtx (bid<4096) + wtrans (bid>=4096) ----------------
__global__ __launch_bounds__(256) void prep(
    const float* __restrict__ x, u16* __restrict__ xb,
    const float* __restrict__ w0, const float* __restrict__ w1,
    const float* __restrict__ w2, const float* __restrict__ w3,
    u16* __restrict__ o0, u16* __restrict__ o1, u16* __restrict__ o2,
    u16* __restrict__ o3) {
  __shared__ float Tsh[64][65];
  const int bid = blockIdx.x;
  const int tid = threadIdx.x;
  if (bid < 4096) {  // x -> bf16
    const size_t i = ((size_t)bid * 256 + tid) * 8;
    const float4 a = *(const float4*)(x + i);
    const float4 b = *(const float4*)(x + i + 4);
    alignas(16) u16 t[8] = {bfc(a.x), bfc(a.y), bfc(a.z), bfc(a.w),
                            bfc(b.x), bfc(b.y), bfc(b.z), bfc(b.w)};
    *(s8v*)(xb + i) = *(const s8v*)t;
    return;
  }
  const int idx = bid - 4096;  // 0..1023
  const int wz = idx >> 8, wy = (idx >> 4) & 15, wx = idx & 15;
  const float* W;
  u16* O;
  switch (wz) {
    case 0: W = w0; O = o0; break;
    case 1: W = w1; O = o1; break;
    case 2: W = w2; O = o2; break;
    default: W = w3; O = o3; break;
  }
  const int n0 = wx * 64, k0 = wy * 64;
  {
    const int rk = tid >> 2, c0 = (tid & 3) * 16;
#pragma unroll
    for (int u = 0; u < 4; ++u) {
      const float4 v = *(const float4*)&W[(size_t)(k0 + rk) * Cn + n0 + c0 + u * 4];
      Tsh[rk][c0 + u * 4 + 0] = v.x;
      Tsh[rk][c0 + u * 4 + 1] = v.y;
      Tsh[rk][c0 + u * 4 + 2] = v.z;
      Tsh[rk][c0 + u * 4 + 3] = v.w;
    }
  }
  __syncthreads();
  {
    const int rn = tid >> 2, ck0 = (tid & 3) * 16;
    alignas(16) u16 t[16];
#pragma unroll
    for (int u = 0; u < 16; ++u) t[u] = bfc(Tsh[ck0 + u][rn]);
    *(s8v*)&O[(size_t)(n0 + rn) * Cn + k0 + ck0] = *(const s8v*)&t[0];
    *(s8v*)&O[(size_t)(n0 + rn) * Cn + k0 + ck0 + 8] = *(const s8v*)&t[8];
  }
}

// ---------------- GEMM body: BK=64, XOR-swizzled LDS ----------------
// OUT_MODE 0: bf16  1: V^T head-major pi-permuted  2: fp32  3: bf16 * QSCALE
template <int OUT_MODE>
__device__ __forceinline__ void gemm_body(const u16* __restrict__ A,
                                          const u16* __restrict__ Bt,
                                          void* __restrict__ Cout, int bm,
                                          int bn, u16* As, u16* Bs) {
  const int N = Cn, K = Cn;
  const int tid = threadIdx.x;
  const int l = tid & 63, w = tid >> 6;
  const int lr = l & 15, lh = l >> 4;
  const int wm = (w >> 1) * 64, wn = (w & 1) * 64;
  const u16* Ab = A + (size_t)(bm * 128) * K;
  const u16* Bb = Bt + (size_t)(bn * 128) * K;
  const int sw = lr & 7;
  f4v acc[4][4] = {};
  for (int k0 = 0; k0 < K; k0 += 64) {
    __syncthreads();  // readers done with LDS
#pragma unroll
    for (int i = 0; i < 4; ++i) {
      const int s = tid + 256 * i;
      const int r = s >> 3, c = s & 7;
      gl_lds16(Ab + (size_t)r * K + k0 + ((c ^ (r & 7)) * 8), &As[s * 8]);
    }
#pragma unroll
    for (int i = 0; i < 4; ++i) {
      const int s = tid + 256 * i;
      const int r = s >> 3, c = s & 7;
      gl_lds16(Bb + (size_t)r * K + k0 + ((c ^ (r & 7)) * 8), &Bs[s * 8]);
    }
    __syncthreads();  // stage complete (barrier drains vmcnt)
#pragma unroll
    for (int half = 0; half < 2; ++half) {
      s8v af[4], bfr[4];
#pragma unroll
      for (int i = 0; i < 4; ++i)
        af[i] = *(const s8v*)&As[(wm + i * 16 + lr) * 64 +
                                 (((half * 4 + lh) ^ sw) * 8)];
#pragma unroll
      for (int j = 0; j < 4; ++j)
        bfr[j] = *(const s8v*)&Bs[(wn + j * 16 + lr) * 64 +
                                  (((half * 4 + lh) ^ sw) * 8)];
      __builtin_amdgcn_s_setprio(1);
#pragma unroll
      for (int i = 0; i < 4; ++i)
#pragma unroll
        for (int j = 0; j < 4; ++j)
          acc[i][j] = mfma16(af[i], bfr[j], acc[i][j]);
      __builtin_amdgcn_s_setprio(0);
    }
  }
  // D layout: col = lane&15, row = (lane>>4)*4 + reg  [m89]
  if (OUT_MODE == 2) {
    float* Cf = (float*)Cout;
#pragma unroll
    for (int i = 0; i < 4; ++i) {
      const int row = bm * 128 + wm + i * 16 + lh * 4;
#pragma unroll
      for (int j = 0; j < 4; ++j) {
        const int col = bn * 128 + wn + j * 16 + lr;
#pragma unroll
        for (int r = 0; r < 4; ++r)
          Cf[(size_t)(row + r) * N + col] = acc[i][j][r];
      }
    }
  } else if (OUT_MODE == 0 || OUT_MODE == 3) {
    u16* Cb = (u16*)Cout;
    const float sc = (OUT_MODE == 3) ? QSCALE : 1.0f;
#pragma unroll
    for (int i = 0; i < 4; ++i) {
      const int row = bm * 128 + wm + i * 16 + lh * 4;
#pragma unroll
      for (int j = 0; j < 4; ++j) {
        const int col = bn * 128 + wn + j * 16 + lr;
#pragma unroll
        for (int r = 0; r < 4; ++r)
          Cb[(size_t)(row + r) * N + col] = bfc(acc[i][j][r] * sc);
      }
    }
  } else {
    // V^T head-major pi-permuted: within each 128-t tile, original
    // t = 32p+16s+4lh+j stored at p*32+lh*8+s*4+j (4-groups stay contiguous)
    u16* Vt = (u16*)Cout;
#pragma unroll
    for (int i = 0; i < 4; ++i) {
      const int row0 = bm * 128 + wm + i * 16 + lh * 4;
      const int bq = row0 >> 11;
      const int t0g = row0 & 2047;
      const int tau = t0g & 127;
      const int taup = ((tau >> 5) << 5) | (((tau >> 2) & 3) << 3) |
                       (((tau >> 4) & 1) << 2);
      const int t0p = (t0g & ~127) | taup;
#pragma unroll
      for (int j = 0; j < 4; ++j) {
        const int col = bn * 128 + wn + j * 16 + lr;
        const int hh = col >> 6, dd = col & 63;
        alignas(8) u16 t4[4];
#pragma unroll
        for (int r = 0; r < 4; ++r) t4[r] = bfc(acc[i][j][r]);
        *(s4v*)&Vt[((size_t)((bq * 16 + hh) * 64 + dd)) * Tn + t0p] =
            *(const s4v*)t4;
      }
    }
  }
}

// Fused q/k/v projection: 1536 blocks, bm-sliced XCD map.
__global__ __launch_bounds__(256) void gemm_qkv(
    const u16* __restrict__ A, const u16* __restrict__ btq,
    const u16* __restrict__ btk, const u16* __restrict__ btv,
    u16* __restrict__ qb, u16* __restrict__ kb, u16* __restrict__ vt) {
  __shared__ __align__(16) u16 As[8192], Bs[8192];  // 32 KB
  const int bid = blockIdx.x;  // 0..1535
  const int xcd = bid & 7, j = bid >> 3;
  const int bm = xcd * 8 + (j & 7);
  const int combo = j >> 3;  // 0..23
  const int which = combo >> 3, bn = combo & 7;
  if (which == 0)
    gemm_body<3>(A, btq, qb, bm, bn, As, Bs);  // Q pre-scaled
  else if (which == 1)
    gemm_body<0>(A, btk, kb, bm, bn, As, Bs);
  else
    gemm_body<1>(A, btv, vt, bm, bn, As, Bs);
}

template <int OUT_MODE>
__global__ __launch_bounds__(256) void gemm_bt(const u16* __restrict__ A,
                                               const u16* __restrict__ Bt,
                                               void* __restrict__ Cout) {
  __shared__ __align__(16) u16 As[8192], Bs[8192];  // 32 KB
  const int bid = blockIdx.x;  // 0..511
  const int xcd = bid & 7, j = bid >> 3;
  const int bm = xcd * 8 + (j & 7);
  const int bn = j >> 3;  // 0..7
  gemm_body<OUT_MODE>(A, Bt, Cout, bm, bn, As, Bs);
}

// ---------------- Flash attention, KVB=64 unpaired ----------------
// K tile [64 rows][64 d], V^T tile [64 d][64 t] (pi-permuted global),
// both staged via global_load_lds, chunk c holds global chunk c^(row&7).
__device__ __forceinline__ void stage_kv(const u16* __restrict__ kgb,
                                         const u16* __restrict__ vtb,
                                         u16* __restrict__ Kb,
                                         u16* __restrict__ Vb, int k0,
                                         int tid) {
  const int row = tid >> 3, ch = tid & 7;
  gl_lds16(kgb + (size_t)(k0 + row) * Cn + ((ch ^ (row & 7)) * 8),
           &Kb[tid * 8]);
  gl_lds16(vtb + (size_t)row * Tn + k0 + ((ch ^ (row & 7)) * 8),
           &Vb[tid * 8]);
}

// One 128q x 64k tile-step. exp/pack fused into the PV p-loop (pa transient).
__device__ __forceinline__ void attn_step(const s8v (&aq)[2],
                                          const u16* __restrict__ Ks,
                                          const u16* __restrict__ Vs, int kb0,
                                          int kb1, const int (&vch)[2], int ln,
                                          int lh, bool diag, int k0, int qg,
                                          float& m_i, float& l_i, f4v* o) {
  f4v s[4] = {};
  __builtin_amdgcn_s_setprio(1);
#pragma unroll
  for (int n = 0; n < 4; ++n) {
    const s8v bk0 = *(const s8v*)&Ks[kb0 + n * 1024];
    const s8v bk1 = *(const s8v*)&Ks[kb1 + n * 1024];
    s[n] = mfma16(bk0, aq[0], s[n]);  // SWAPPED: S^T[k][q]
    s[n] = mfma16(bk1, aq[1], s[n]);
  }
  __builtin_amdgcn_s_setprio(0);
  float rm = -1e30f;
  if (diag) {
#pragma unroll
    for (int n = 0; n < 4; ++n)
#pragma unroll
      for (int r = 0; r < 4; ++r) {
        float x = s[n][r];
        if (k0 + n * 16 + lh * 4 + r > qg) x = -1e30f;
        s[n][r] = x;
        rm = fmaxf(rm, x);
      }
  } else {
#pragma unroll
    for (int n = 0; n < 4; ++n)
      rm = fmaxf(rm, fmaxf(fmaxf(s[n][0], s[n][1]), fmaxf(s[n][2], s[n][3])));
  }
  if (!__all(rm <= m_i + 11.5f)) {  // T13 defer-max
    float rr = fmaxf(rm, __shfl_xor(rm, 16));
    rr = fmaxf(rr, __shfl_xor(rr, 32));
    const float mnew = fmaxf(m_i, rr);
    const float al = ex2(m_i - mnew);
    m_i = mnew;
    l_i *= al;
#pragma unroll
    for (int r = 0; r < 4; ++r) {
      const float ar = __shfl(al, (ln & 48) | (lh * 4 + r));
#pragma unroll
      for (int n2 = 0; n2 < 4; ++n2) o[n2][r] *= ar;
    }
  }
  float rs = 0.f;
  __builtin_amdgcn_s_setprio(1);
#pragma unroll
  for (int p = 0; p < 2; ++p) {
    const float a0 = ex2(s[2 * p][0] - m_i);
    const float a1 = ex2(s[2 * p][1] - m_i);
    const float a2 = ex2(s[2 * p][2] - m_i);
    const float a3 = ex2(s[2 * p][3] - m_i);
    const float b0 = ex2(s[2 * p + 1][0] - m_i);
    const float b1 = ex2(s[2 * p + 1][1] - m_i);
    const float b2 = ex2(s[2 * p + 1][2] - m_i);
    const float b3 = ex2(s[2 * p + 1][3] - m_i);
    rs += ((a0 + a1) + (a2 + a3)) + ((b0 + b1) + (b2 + b3));
    const s4v pa0 = {(short)bfc(a0), (short)bfc(a1), (short)bfc(a2),
                     (short)bfc(a3)};
    const s4v pa1 = {(short)bfc(b0), (short)bfc(b1), (short)bfc(b2),
                     (short)bfc(b3)};
#pragma unroll
    for (int n2 = 0; n2 < 4; ++n2) {
      const s8v vv = *(const s8v*)&Vs[vch[p] + n2 * 1024];
      const s4v lo = {vv[0], vv[1], vv[2], vv[3]};
      const s4v hi = {vv[4], vv[5], vv[6], vv[7]};
      o[n2] = mfma16k16(pa0, lo, o[n2]);  // O[q=lh*4+reg][d=n2*16+lr]
      o[n2] = mfma16k16(pa1, hi, o[n2]);
    }
  }
  __builtin_amdgcn_s_setprio(0);
  l_i += rs;  // per-lane partial; row-reduce deferred to epilogue
}

// Grid 1024 = 16 qt x 64 bh, one 128-row q-tile per block, 512 thr = 8 waves.
// Mapping balances per-CU work: co-resident blocks get qt {p,15-p,p,15-p}.
__global__ __launch_bounds__(512) void attn_big(const u16* __restrict__ qg,
                                                const u16* __restrict__ kg,
                                                const u16* __restrict__ vtg,
                                                u16* __restrict__ yg) {
  __shared__ __align__(16) u16 Ks0[4096], Ks1[4096];  // 8 KB each
  __shared__ __align__(16) u16 Vs0[4096], Vs1[4096];  // 8 KB each
  const int tid = threadIdx.x;
  const int ln = tid & 63, w = tid >> 6;  // wave 0..7
  const int lr = ln & 15, lh = ln >> 4;
  const int bid = blockIdx.x;                   // 0..1023
  const int wg = (bid & 7) * 128 + (bid >> 3);  // bijective XCD chunking
  const int xcd = wg >> 7, gl = (wg >> 5) & 3, r5 = wg & 31;
  const int qt = (gl & 1) ? (15 - (r5 & 7)) : (r5 & 7);
  const int bh = ((gl >> 1) << 5) | (xcd << 2) | (r5 >> 3);
  const int b = bh >> 4, h = bh & 15;
  const int q0 = qt * 128;
  const int nlast = 2 * qt + 1;  // k-tiles 0..nlast (KVB=64)
  const u16* kgb = kg + (size_t)(b * Tn) * Cn + h * 64;
  const u16* vtb = vtg + (size_t)(bh * 64) * Tn;
  // hoisted lane-constant LDS offsets (elements)
  const int kb0 = lr * 64 + ((lh) ^ (lr & 7)) * 8;
  const int kb1 = lr * 64 + ((4 + lh) ^ (lr & 7)) * 8;
  int vch[2];
#pragma unroll
  for (int p = 0; p < 2; ++p)
    vch[p] = lr * 64 + ((p * 4 + lh) ^ (lr & 7)) * 8;
  // Q-hoist: per-wave B-fragments in registers (Q already * QSCALE)
  s8v aq[2];
  {
    const int row = q0 + w * 16 + lr;
#pragma unroll
    for (int kd = 0; kd < 2; ++kd)
      aq[kd] = *(const s8v*)&qg[(size_t)(b * Tn + row) * Cn + h * 64 +
                                kd * 32 + lh * 8];
  }
  const int qgl = q0 + w * 16 + lr;
  float m_i = -1e30f, l_i = 0.f;
  f4v o[4] = {};
  stage_kv(kgb, vtb, Ks0, Vs0, 0, tid);
  __syncthreads();  // buf0 ready (barrier drains vmcnt)
  for (int kt = 0; kt <= nlast; ++kt) {
    const bool cur = kt & 1;
    const u16* Kb = cur ? Ks1 : Ks0;
    const u16* Vb = cur ? Vs1 : Vs0;
    if (kt < nlast)  // async-stage next tile into the other buffer
      stage_kv(kgb, vtb, cur ? Ks0 : Ks1, cur ? Vs0 : Vs1, (kt + 1) * 64,
               tid);
    attn_step(aq, Kb, Vb, kb0, kb1, vch, ln, lh, kt >= 2 * qt, kt * 64, qgl,
              m_i, l_i, o);
    __syncthreads();  // next buffer ready; this buffer's readers done
  }
  {
    float ls = l_i;
    ls += __shfl_xor(ls, 16);
    ls += __shfl_xor(ls, 32);
    const float linv = 1.0f / ls;
#pragma unroll
    for (int r = 0; r < 4; ++r) {
      const float iv = __shfl(linv, (ln & 48) | (lh * 4 + r));
      const int row = q0 + w * 16 + lh * 4 + r;
#pragma unroll
      for (int n2 = 0; n2 < 4; ++n2)
        yg[(size_t)(b * Tn + row) * Cn + h * 64 + n2 * 16 + lr] =
            bfc(o[n2][r] * iv);
    }
  }
}

}  // namespace

extern "C" void kernel_launch(void* const* d_in, const int* in_sizes, int n_in,
                              void* d_out, int out_size, void* d_ws,
                              size_t ws_size, hipStream_t stream) {
  (void)in_sizes; (void)n_in; (void)out_size; (void)ws_size;
  const float* x = (const float*)d_in[0];
  const float* Wk = (const float*)d_in[1];
  const float* Wq = (const float*)d_in[2];
  const float* Wv = (const float*)d_in[3];
  const float* Wp = (const float*)d_in[4];
  float* out = (float*)d_out;
  char* ws = (char*)d_ws;

  u16* xb = (u16*)(ws);              // 16.8 MB
  u16* wqt = (u16*)(ws + 16777216);  // 2 MB each
  u16* wkt = (u16*)(ws + 18874368);
  u16* wvt = (u16*)(ws + 20971520);
  u16* wpt = (u16*)(ws + 23068672);
  u16* qb = (u16*)(ws + 25165824);  // 16.8 MB each
  u16* kb = (u16*)(ws + 41943040);
  u16* vt = (u16*)(ws + 58720256);  // head-major V^T [b][h][d][t], pi-permuted
  u16* yb = (u16*)(ws + 75497472);

  prep<<<dim3(5120), dim3(256), 0, stream>>>(x, xb, Wq, Wk, Wv, Wp, wqt, wkt,
                                             wvt, wpt);
  gemm_qkv<<<dim3(1536), dim3(256), 0, stream>>>(xb, wqt, wkt, wvt, qb, kb,
                                                 vt);
  attn_big<<<dim3(1024), dim3(512), 0, stream>>>(qb, kb, vt, yb);
  gemm_bt<2><<<dim3(512), dim3(256), 0, stream>>>(yb, wpt, out);
}